// Round 8
// baseline (258.944 us; speedup 1.0000x reference)
//
#include <hip/hip_runtime.h>
#include <math.h>

// Rieke cone phototransduction, B=64 T=512 U=1024.
// One thread per (b,u) chain; 511 sequential steps. 1024 waves = 1 wave/SIMD
// (structural cap). Latency-bound. vmcnt retires IN ISSUE ORDER on CDNA, so
// any load-wait also waits all older store-acks -> stores must ack FAST.
// Round 6 lesson: NT stores ack from the HBM path (slow) and sat at the head
// of the vmcnt queue every chunk. This round: plain cached stores (ack at L2).

#define TT 512
#define UU 1024
#define UN 16            // chunk depth; max outstanding VMEM = 48 < 63
#define DTSTEP 0.008f

template <bool FAST>
__device__ __forceinline__ void run_chain(
    const float* __restrict__ xrow, float* __restrict__ orow,
    float sigma, float phi, float eta, float beta, float cgmp2cur,
    float cgmphill, float cdark, float betaSlow, float hillcoef,
    float hillaff, float gam, float gdark)
{
    // Derived constants (one-time, full precision)
    const float darkCurrent = powf(gdark, cgmphill) * cgmp2cur * 0.5f;
    const float gdark_e = powf(2.0f * darkCurrent / cgmp2cur, 1.0f / cgmphill);
    const float cur2ca = beta * cdark / darkCurrent;
    const float smax = eta / phi * gdark_e *
                       (1.0f + powf(cdark / hillaff, hillcoef));

    // Loop-invariant folds
    const float Ar   = 1.0f - DTSTEP * sigma;
    const float icd  = 1.0f / cdark;
    const float kc   = cur2ca * cgmp2cur;
    const float iha  = 1.0f / hillaff;
    const float outk = -0.5f * cgmp2cur;
    const float dtbs = DTSTEP * betaSlow;

    // Initial state
    float g  = gdark_e;
    float s  = gdark_e * eta / phi;
    float c  = cdark;
    float cs = cdark;
    float r, p;
    {
        float x0 = xrow[0];
        r = x0 * gam / sigma;
        p = (eta + r) / phi;
    }
    float gp = FAST ? g * g * g : __powf(g, cgmphill);

    orow[0] = 0.0f;  // g[:,0,:] stays zero in reference

    auto step = [&](float x, float& outv) {
        float rn  = fmaf(Ar, r, gam * x);
        float pn  = fmaf(DTSTEP, (r + eta) - phi * p, p);
        float den = fmaf(cs, icd, 1.0f);
        float cn  = fmaf(DTSTEP,
                         fmaf(-beta, c, kc * gp * __builtin_amdgcn_rcpf(den)),
                         c);
        float csn = fmaf(-dtbs, cs - c, cs);
        float sn;
        if (FAST) {
            float t2 = cn * iha;
            t2 *= t2;
            sn = smax * __builtin_amdgcn_rcpf(fmaf(t2, t2, 1.0f));
        } else {
            sn = smax / (1.0f + __powf(cn * iha, hillcoef));
        }
        float gn  = fmaf(DTSTEP, fmaf(-p, g, s), g);  // uses OLD s, p
        float gpn = FAST ? gn * gn * gn : __powf(gn, cgmphill);
        outv = outk * gpn;
        g = gn; s = sn; c = cn; cs = csn; p = pn; r = rn; gp = gpn;
    };

    float bufA[UN], bufB[UN], ob[UN];

    // Prologue: chunk 0 -> A
#pragma unroll
    for (int k = 0; k < UN; ++k) bufA[k] = xrow[k * UU];

    const float* xln = xrow + UN * UU;  // load base for next chunk
    float* op = orow + UU;              // out base (t index 1)

    // Chunks 0..29 as 15 ping-pong pairs, then chunk 30, then epilogue(31).
    for (int pair = 0; pair < 15; ++pair) {
        // even chunk: prefetch -> B, compute A, burst-store
#pragma unroll
        for (int k = 0; k < UN; ++k) bufB[k] = xln[k * UU];
        __builtin_amdgcn_sched_barrier(0);
#pragma unroll
        for (int k = 0; k < UN; ++k) step(bufA[k], ob[k]);
        __builtin_amdgcn_sched_barrier(0);
#pragma unroll
        for (int k = 0; k < UN; ++k) op[k * UU] = ob[k];
        __builtin_amdgcn_sched_barrier(0);
        xln += UN * UU; op += UN * UU;

        // odd chunk: prefetch -> A, compute B, burst-store
#pragma unroll
        for (int k = 0; k < UN; ++k) bufA[k] = xln[k * UU];
        __builtin_amdgcn_sched_barrier(0);
#pragma unroll
        for (int k = 0; k < UN; ++k) step(bufB[k], ob[k]);
        __builtin_amdgcn_sched_barrier(0);
#pragma unroll
        for (int k = 0; k < UN; ++k) op[k * UU] = ob[k];
        __builtin_amdgcn_sched_barrier(0);
        xln += UN * UU; op += UN * UU;
    }

    // Chunk 30 (in A): prefetch chunk 31 -> B, compute, store
#pragma unroll
    for (int k = 0; k < UN; ++k) bufB[k] = xln[k * UU];
    __builtin_amdgcn_sched_barrier(0);
#pragma unroll
    for (int k = 0; k < UN; ++k) step(bufA[k], ob[k]);
    __builtin_amdgcn_sched_barrier(0);
#pragma unroll
    for (int k = 0; k < UN; ++k) op[k * UU] = ob[k];
    op += UN * UU;

    // Epilogue: chunk 31 (in B), 15 steps -> total 511 steps (t=1..511)
#pragma unroll
    for (int k = 0; k < UN - 1; ++k) {
        float o;
        step(bufB[k], o);
        op[k * UU] = o;
    }
}

__global__ __launch_bounds__(256, 1) void prfr_kernel(
    const float* __restrict__ X,
    const float* __restrict__ sigma_p, const float* __restrict__ phi_p,
    const float* __restrict__ eta_p,   const float* __restrict__ beta_p,
    const float* __restrict__ cgmp2cur_p, const float* __restrict__ cgmphill_p,
    const float* __restrict__ cdark_p, const float* __restrict__ betaSlow_p,
    const float* __restrict__ hillcoef_p, const float* __restrict__ hillaff_p,
    const float* __restrict__ gamma_p, const float* __restrict__ gdark_p,
    float* __restrict__ out, int total)
{
    const int idx = blockIdx.x * blockDim.x + threadIdx.x;
    if (idx >= total) return;
    const int u = idx & (UU - 1);
    const int b = idx >> 10;

    const float* xrow = X + (long)b * (TT * UU) + u;
    float* orow = out + (long)b * (TT * UU) + u;

    const float sigma = sigma_p[u], phi = phi_p[u], eta = eta_p[u];
    const float beta = beta_p[u], cgmp2cur = cgmp2cur_p[u];
    const float cgmphill = cgmphill_p[u], cdark = cdark_p[u];
    const float betaSlow = betaSlow_p[u], hillcoef = hillcoef_p[u];
    const float hillaff = hillaff_p[u], gam = gamma_p[u], gdark = gdark_p[u];

    if (cgmphill == 3.0f && hillcoef == 4.0f) {
        run_chain<true>(xrow, orow, sigma, phi, eta, beta, cgmp2cur, cgmphill,
                        cdark, betaSlow, hillcoef, hillaff, gam, gdark);
    } else {
        run_chain<false>(xrow, orow, sigma, phi, eta, beta, cgmp2cur, cgmphill,
                         cdark, betaSlow, hillcoef, hillaff, gam, gdark);
    }
}

extern "C" void kernel_launch(void* const* d_in, const int* in_sizes, int n_in,
                              void* d_out, int out_size, void* d_ws, size_t ws_size,
                              hipStream_t stream)
{
    const float* X = (const float*)d_in[0];
    const int B = in_sizes[0] / (TT * UU);
    const int total = B * UU;
    const int block = 256;
    const int grid = (total + block - 1) / block;
    prfr_kernel<<<grid, block, 0, stream>>>(
        X,
        (const float*)d_in[1],  (const float*)d_in[2],  (const float*)d_in[3],
        (const float*)d_in[4],  (const float*)d_in[5],  (const float*)d_in[6],
        (const float*)d_in[7],  (const float*)d_in[8],  (const float*)d_in[9],
        (const float*)d_in[10], (const float*)d_in[11], (const float*)d_in[12],
        (float*)d_out, total);
}

// Round 9
// 257.310 us; speedup vs baseline: 1.0064x; 1.0064x over previous
//
#include <hip/hip_runtime.h>
#include <math.h>

// Rieke cone phototransduction, B=64 T=512 U=1024.
// One thread per (b,u) chain; 511 sequential steps; 1024 waves (1/SIMD).
// R8 lesson: VGPR=56 proved the compiler sank my register prefetch (needs
// >=85 regs) -> per-step exposed ~600cyc load latency. Fix: stage X chunks
// into per-wave LDS via global_load_lds (unsinkable, zero VGPR cost),
// double-buffered, with exact counted vmcnt waits (never vmcnt(0) in loop).

#define TT 512
#define UU 1024
#define UN 16            // chunk depth; vmcnt(16) strings below assume this
#define DTSTEP 0.008f

__device__ __forceinline__ void gload_lds(const float* g, float* l) {
    __builtin_amdgcn_global_load_lds(
        (__attribute__((address_space(1))) void*)(uintptr_t)g,
        (__attribute__((address_space(3))) void*)l, 4, 0, 0);
}

template <bool FAST>
__device__ __forceinline__ void run_chain(
    const float* __restrict__ xrow, float* __restrict__ orow,
    float* __restrict__ swave,  // &smem[wave][0][0][0]: [2][UN][64] floats
    int lane,
    float sigma, float phi, float eta, float beta, float cgmp2cur,
    float cgmphill, float cdark, float betaSlow, float hillcoef,
    float hillaff, float gam, float gdark)
{
    // Derived constants
    const float darkCurrent = powf(gdark, cgmphill) * cgmp2cur * 0.5f;
    const float gdark_e = powf(2.0f * darkCurrent / cgmp2cur, 1.0f / cgmphill);
    const float cur2ca = beta * cdark / darkCurrent;
    const float smax = eta / phi * gdark_e *
                       (1.0f + powf(cdark / hillaff, hillcoef));

    const float Ar   = 1.0f - DTSTEP * sigma;
    const float icd  = 1.0f / cdark;
    const float kc   = cur2ca * cgmp2cur;
    const float iha  = 1.0f / hillaff;
    const float outk = -0.5f * cgmp2cur;
    const float dtbs = DTSTEP * betaSlow;

    // Initial state (x0 read + t=0 output store happen in prologue;
    // both drained by the one-time vmcnt(0) at phase 0).
    float g  = gdark_e;
    float s  = gdark_e * eta / phi;
    float c  = cdark;
    float cs = cdark;
    float r, p;
    {
        float x0 = xrow[0];
        r = x0 * gam / sigma;
        p = (eta + r) / phi;
    }
    float gp = FAST ? g * g * g : __powf(g, cgmphill);

    orow[0] = 0.0f;  // g[:,0,:] stays zero in reference

    auto step = [&](float x, float& outv) {
        float rn  = fmaf(Ar, r, gam * x);
        float pn  = fmaf(DTSTEP, (r + eta) - phi * p, p);
        float den = fmaf(cs, icd, 1.0f);
        float cn  = fmaf(DTSTEP,
                         fmaf(-beta, c, kc * gp * __builtin_amdgcn_rcpf(den)),
                         c);
        float csn = fmaf(-dtbs, cs - c, cs);
        float sn;
        if (FAST) {
            float t2 = cn * iha;
            t2 *= t2;
            sn = smax * __builtin_amdgcn_rcpf(fmaf(t2, t2, 1.0f));
        } else {
            sn = smax / (1.0f + __powf(cn * iha, hillcoef));
        }
        float gn  = fmaf(DTSTEP, fmaf(-p, g, s), g);  // uses OLD s, p
        float gpn = FAST ? gn * gn * gn : __powf(gn, cgmphill);
        outv = outk * gpn;
        g = gn; s = sn; c = cn; cs = csn; p = pn; r = rn; gp = gpn;
    };

    // Prologue: stage chunk 0 into LDS buffer 0.
#pragma unroll
    for (int k = 0; k < UN; ++k)
        gload_lds(xrow + k * UU, swave + k * 64);

    const float* xst = xrow + UN * UU;  // stage ptr (next chunk)
    float* op = orow + UU;              // out ptr (t = n*UN+1)

    // Phases 0..30: wait chunk n, read it, stage n+1, compute+store 16.
    for (int n = 0; n < TT / UN - 1; ++n) {
        if (n == 0) {
            asm volatile("s_waitcnt vmcnt(0)" ::: "memory");   // one-time
        } else {
            // exact: stage(n) retired <=> outstanding <= stores(n-1)+stage(n+1)... 
            // queue = [stage(n)][stores(n-1) 16][stage(n+1) not yet issued]
            asm volatile("s_waitcnt vmcnt(16)" ::: "memory");
        }
        __builtin_amdgcn_sched_barrier(0);
        const int p2 = (n & 1) * (UN * 64);
        float xa[UN];
#pragma unroll
        for (int k = 0; k < UN; ++k) xa[k] = swave[p2 + k * 64 + lane];
        __builtin_amdgcn_sched_barrier(0);
        const int q2 = ((n & 1) ^ 1) * (UN * 64);
#pragma unroll
        for (int k = 0; k < UN; ++k)
            gload_lds(xst + k * UU, swave + q2 + k * 64);
        __builtin_amdgcn_sched_barrier(0);
#pragma unroll
        for (int k = 0; k < UN; ++k) {
            float o;
            step(xa[k], o);
            op[k * UU] = o;
        }
        xst += UN * UU;
        op += UN * UU;
    }

    // Phase 31: wait stage(31) (younger: 16 stores of chunk 30), 15 steps.
    asm volatile("s_waitcnt vmcnt(16)" ::: "memory");
    __builtin_amdgcn_sched_barrier(0);
    {
        const int p2 = (31 & 1) * (UN * 64);
        float xa[UN];
#pragma unroll
        for (int k = 0; k < UN; ++k) xa[k] = swave[p2 + k * 64 + lane];
#pragma unroll
        for (int k = 0; k < UN - 1; ++k) {
            float o;
            step(xa[k], o);
            op[k * UU] = o;
        }
    }
}

__global__ __launch_bounds__(256, 1) void prfr_kernel(
    const float* __restrict__ X,
    const float* __restrict__ sigma_p, const float* __restrict__ phi_p,
    const float* __restrict__ eta_p,   const float* __restrict__ beta_p,
    const float* __restrict__ cgmp2cur_p, const float* __restrict__ cgmphill_p,
    const float* __restrict__ cdark_p, const float* __restrict__ betaSlow_p,
    const float* __restrict__ hillcoef_p, const float* __restrict__ hillaff_p,
    const float* __restrict__ gamma_p, const float* __restrict__ gdark_p,
    float* __restrict__ out, int total)
{
    __shared__ float smem[4][2][UN][64];   // 32 KiB: per-wave double buffer

    const int idx = blockIdx.x * blockDim.x + threadIdx.x;
    if (idx >= total) return;
    const int u = idx & (UU - 1);
    const int b = idx >> 10;
    const int w = __builtin_amdgcn_readfirstlane(threadIdx.x >> 6);
    const int lane = threadIdx.x & 63;

    const float* xrow = X + (long)b * (TT * UU) + u;
    float* orow = out + (long)b * (TT * UU) + u;

    const float sigma = sigma_p[u], phi = phi_p[u], eta = eta_p[u];
    const float beta = beta_p[u], cgmp2cur = cgmp2cur_p[u];
    const float cgmphill = cgmphill_p[u], cdark = cdark_p[u];
    const float betaSlow = betaSlow_p[u], hillcoef = hillcoef_p[u];
    const float hillaff = hillaff_p[u], gam = gamma_p[u], gdark = gdark_p[u];

    float* swave = &smem[w][0][0][0];

    if (cgmphill == 3.0f && hillcoef == 4.0f) {
        run_chain<true>(xrow, orow, swave, lane, sigma, phi, eta, beta,
                        cgmp2cur, cgmphill, cdark, betaSlow, hillcoef,
                        hillaff, gam, gdark);
    } else {
        run_chain<false>(xrow, orow, swave, lane, sigma, phi, eta, beta,
                         cgmp2cur, cgmphill, cdark, betaSlow, hillcoef,
                         hillaff, gam, gdark);
    }
}

extern "C" void kernel_launch(void* const* d_in, const int* in_sizes, int n_in,
                              void* d_out, int out_size, void* d_ws, size_t ws_size,
                              hipStream_t stream)
{
    const float* X = (const float*)d_in[0];
    const int B = in_sizes[0] / (TT * UU);
    const int total = B * UU;
    const int block = 256;
    const int grid = (total + block - 1) / block;
    prfr_kernel<<<grid, block, 0, stream>>>(
        X,
        (const float*)d_in[1],  (const float*)d_in[2],  (const float*)d_in[3],
        (const float*)d_in[4],  (const float*)d_in[5],  (const float*)d_in[6],
        (const float*)d_in[7],  (const float*)d_in[8],  (const float*)d_in[9],
        (const float*)d_in[10], (const float*)d_in[11], (const float*)d_in[12],
        (float*)d_out, total);
}

// Round 10
// 255.605 us; speedup vs baseline: 1.0131x; 1.0067x over previous
//
#include <hip/hip_runtime.h>
#include <math.h>

// Rieke cone phototransduction, B=64 T=512 U=1024. One thread per chain,
// 511 serial steps, 1024 waves (1/SIMD). r5-r9: three schedule variants
// identical (~82us, VALU 27%) => not memory-latency-bound; attacking
// instruction issue: 21-op step, dwordx4 LDS staging (4 instr/phase),
// immediate-offset ds_reads, 32-bit store indexing.

#define TT 512
#define UU 1024
#define DTSTEP 0.008f

__device__ __forceinline__ void gload16(const float* g, float* l) {
    __builtin_amdgcn_global_load_lds(
        (__attribute__((address_space(1))) void*)(uintptr_t)g,
        (__attribute__((address_space(3))) void*)l, 16, 0, 0);
}

// ---------------- FAST path: cgmphill==3, hillcoef==4 ----------------
__device__ __forceinline__ void run_fast(
    const float* __restrict__ xrow, float* __restrict__ out, unsigned ob,
    const float* gstage, float* __restrict__ wlds, int lane,
    float sigma, float phi, float eta, float beta, float cgmp2cur,
    float cdark, float betaSlow, float hillaff, float gam, float gdark)
{
    // Derived constants (one-time)
    const float darkCurrent = gdark * gdark * gdark * cgmp2cur * 0.5f;
    const float gdark_e = gdark;  // (2*dark/cgmp2cur)^(1/3) == gdark exactly
    const float cur2ca = beta * cdark / darkCurrent;
    const float ha2 = (cdark / hillaff) * (cdark / hillaff);
    const float smax = eta / phi * gdark_e * (1.0f + ha2 * ha2);

    const float Ar   = 1.0f - DTSTEP * sigma;
    const float P1   = 1.0f - DTSTEP * phi;
    const float Ke   = DTSTEP * eta;
    const float icd  = 1.0f / cdark;
    const float KC   = DTSTEP * cur2ca * cgmp2cur;
    const float C1   = 1.0f - DTSTEP * beta;
    const float dtbs = DTSTEP * betaSlow;
    const float iha  = 1.0f / hillaff;
    const float outk = -0.5f * cgmp2cur;

    float g  = gdark_e;
    float s  = gdark_e * eta / phi;
    float c  = cdark;
    float cs = cdark;
    float x0 = xrow[0];
    float r  = x0 * gam / sigma;
    float p  = (eta + r) / phi;
    float gp = g * g * g;

    out[ob - UU] = 0.0f;   // t = 0 output

    // Prologue: stage chunk 0 (4 x dwordx4 global_load_lds = 16 rows)
#pragma unroll
    for (int j = 0; j < 4; ++j) {
        gload16(gstage, wlds + j * 256);
        gstage += 4 * UU;
    }

    auto step = [&](float x, float& o) {
        float rn  = fmaf(Ar, r, gam * x);
        float pn  = fmaf(P1, p, fmaf(DTSTEP, r, Ke));
        float den = fmaf(cs, icd, 1.0f);
        float rd  = __builtin_amdgcn_rcpf(den);
        float cn  = fmaf(KC, gp * rd, C1 * c);
        float csn = fmaf(-dtbs, cs - c, cs);
        float t2  = cn * iha;
        t2 *= t2;
        float sn  = smax * __builtin_amdgcn_rcpf(fmaf(t2, t2, 1.0f));
        float gn  = fmaf(DTSTEP, fmaf(-p, g, s), g);   // OLD s, p
        float gpn = gn * gn * gn;
        o = outk * gpn;
        g = gn; s = sn; c = cn; cs = csn; p = pn; r = rn; gp = gpn;
    };

    // Phase body: wait, stage next (buf^1), ds_read buf, 16 steps + stores.
    auto phase = [&](int buf, bool dostage, bool first) {
        if (first) asm volatile("s_waitcnt vmcnt(0)" ::: "memory");
        else       asm volatile("s_waitcnt vmcnt(16)" ::: "memory");
        __builtin_amdgcn_sched_barrier(0);
        if (dostage) {
#pragma unroll
            for (int j = 0; j < 4; ++j) {
                gload16(gstage, wlds + (buf ^ 1) * 1024 + j * 256);
                gstage += 4 * UU;
            }
        }
        __builtin_amdgcn_sched_barrier(0);
        const float* rb = wlds + buf * 1024 + lane;
        float xa[16];
#pragma unroll
        for (int k = 0; k < 16; ++k) xa[k] = rb[k * 64];
        __builtin_amdgcn_sched_barrier(0);
#pragma unroll
        for (int k = 0; k < 16; ++k) {
            float o;
            step(xa[k], o);
            out[ob + (unsigned)(k * UU)] = o;
        }
        ob += 16u * UU;
    };

    phase(0, true, true);                       // phase 0
    for (int n2 = 0; n2 < 15; ++n2) {           // phases 1..30
        phase(1, true, false);
        phase(0, true, false);
    }
    // Phase 31: 15 steps, no staging
    asm volatile("s_waitcnt vmcnt(16)" ::: "memory");
    __builtin_amdgcn_sched_barrier(0);
    {
        const float* rb = wlds + 1024 + lane;
        float xa[16];
#pragma unroll
        for (int k = 0; k < 16; ++k) xa[k] = rb[k * 64];
#pragma unroll
        for (int k = 0; k < 15; ++k) {
            float o;
            step(xa[k], o);
            out[ob + (unsigned)(k * UU)] = o;
        }
    }
}

// ---------------- generic fallback (never taken for these inputs) ----
__device__ void run_generic(
    const float* __restrict__ xrow, float* __restrict__ out, unsigned ob,
    float sigma, float phi, float eta, float beta, float cgmp2cur,
    float cgmphill, float cdark, float betaSlow, float hillcoef,
    float hillaff, float gam, float gdark)
{
    const float darkCurrent = powf(gdark, cgmphill) * cgmp2cur * 0.5f;
    const float gdark_e = powf(2.0f * darkCurrent / cgmp2cur, 1.0f / cgmphill);
    const float cur2ca = beta * cdark / darkCurrent;
    const float smax = eta / phi * gdark_e *
                       (1.0f + powf(cdark / hillaff, hillcoef));
    float g  = gdark_e;
    float s  = gdark_e * eta / phi;
    float c  = cdark;
    float cs = cdark;
    float x0 = xrow[0];
    float r  = x0 * gam / sigma;
    float p  = (eta + r) / phi;
    out[ob - UU] = 0.0f;
    for (int t = 1; t < TT; ++t) {
        float x  = xrow[(t - 1) * UU];
        float rn = r + DTSTEP * (-sigma * r) + gam * x;
        float pn = p + DTSTEP * (r + eta - phi * p);
        float cn = c + DTSTEP * (cur2ca * cgmp2cur * powf(g, cgmphill)
                                 / (1.0f + cs / cdark) - beta * c);
        float csn = cs - DTSTEP * (betaSlow * (cs - c));
        float sn  = smax / (1.0f + powf(cn / hillaff, hillcoef));
        float gn  = g + DTSTEP * (s - p * g);
        out[ob + (unsigned)((t - 1) * UU)] =
            -(cgmp2cur * powf(gn, cgmphill)) * 0.5f;
        g = gn; s = sn; c = cn; cs = csn; p = pn; r = rn;
    }
}

__global__ __launch_bounds__(256, 1) void prfr_kernel(
    const float* __restrict__ X,
    const float* __restrict__ sigma_p, const float* __restrict__ phi_p,
    const float* __restrict__ eta_p,   const float* __restrict__ beta_p,
    const float* __restrict__ cgmp2cur_p, const float* __restrict__ cgmphill_p,
    const float* __restrict__ cdark_p, const float* __restrict__ betaSlow_p,
    const float* __restrict__ hillcoef_p, const float* __restrict__ hillaff_p,
    const float* __restrict__ gamma_p, const float* __restrict__ gdark_p,
    float* __restrict__ out, int total)
{
    __shared__ float smem[4][2][16][64];   // 32 KiB: per-wave double buffer

    const int idx = blockIdx.x * blockDim.x + threadIdx.x;
    if (idx >= total) return;
    const int u = idx & (UU - 1);
    const int b = idx >> 10;
    const int w = __builtin_amdgcn_readfirstlane(threadIdx.x >> 6);
    const int lane = threadIdx.x & 63;

    const float* xrow = X + (size_t)b * (TT * UU) + u;
    const unsigned ob = (unsigned)b * (TT * UU) + UU + (unsigned)u;  // t=1

    // staging source: lane l covers row (l>>4), u-quad 4*(l&15) of its wave
    const int uq = (u - lane) + 4 * (lane & 15);
    const float* gstage = X + ((size_t)b * TT + (lane >> 4)) * UU + uq;

    const float sigma = sigma_p[u], phi = phi_p[u], eta = eta_p[u];
    const float beta = beta_p[u], cgmp2cur = cgmp2cur_p[u];
    const float cgmphill = cgmphill_p[u], cdark = cdark_p[u];
    const float betaSlow = betaSlow_p[u], hillcoef = hillcoef_p[u];
    const float hillaff = hillaff_p[u], gam = gamma_p[u], gdark = gdark_p[u];

    if (cgmphill == 3.0f && hillcoef == 4.0f) {
        run_fast(xrow, out, ob, gstage, &smem[w][0][0][0], lane,
                 sigma, phi, eta, beta, cgmp2cur, cdark, betaSlow,
                 hillaff, gam, gdark);
    } else {
        run_generic(xrow, out, ob, sigma, phi, eta, beta, cgmp2cur,
                    cgmphill, cdark, betaSlow, hillcoef, hillaff, gam, gdark);
    }
}

extern "C" void kernel_launch(void* const* d_in, const int* in_sizes, int n_in,
                              void* d_out, int out_size, void* d_ws, size_t ws_size,
                              hipStream_t stream)
{
    const float* X = (const float*)d_in[0];
    const int B = in_sizes[0] / (TT * UU);
    const int total = B * UU;
    const int block = 256;
    const int grid = (total + block - 1) / block;
    prfr_kernel<<<grid, block, 0, stream>>>(
        X,
        (const float*)d_in[1],  (const float*)d_in[2],  (const float*)d_in[3],
        (const float*)d_in[4],  (const float*)d_in[5],  (const float*)d_in[6],
        (const float*)d_in[7],  (const float*)d_in[8],  (const float*)d_in[9],
        (const float*)d_in[10], (const float*)d_in[11], (const float*)d_in[12],
        (float*)d_out, total);
}

// Round 11
// 253.475 us; speedup vs baseline: 1.0216x; 1.0084x over previous
//
#include <hip/hip_runtime.h>
#include <math.h>

// Rieke cone phototransduction, B=64 T=512 U=1024.
// r5-r10: all schedules pin at 201MB/82us = 2.45 TB/s -> memory-bound at a
// PATTERN ceiling (256B granules @ stride 4KB, 1024 streams), not peak BW.
// This round: block=(b, u-quarter) owns contiguous 1KB rows; LDS-tile both
// directions; burst float4 stores so DRAM sees 1KB-contiguous granules and
// sibling blocks complete each 4KB row. Raw s_barrier + counted vmcnt.

#define TT 512
#define UU 1024
#define DTSTEP 0.008f

__device__ __forceinline__ void gload16(const float* g, float* l) {
    __builtin_amdgcn_global_load_lds(
        (__attribute__((address_space(1))) void*)(uintptr_t)g,
        (__attribute__((address_space(3))) void*)l, 16, 0, 0);
}

// ---------------- generic fallback (params deviate; never hit here) ----
__device__ void run_generic(
    const float* __restrict__ xrow, float* __restrict__ orow,
    float sigma, float phi, float eta, float beta, float cgmp2cur,
    float cgmphill, float cdark, float betaSlow, float hillcoef,
    float hillaff, float gam, float gdark)
{
    const float darkCurrent = powf(gdark, cgmphill) * cgmp2cur * 0.5f;
    const float gdark_e = powf(2.0f * darkCurrent / cgmp2cur, 1.0f / cgmphill);
    const float cur2ca = beta * cdark / darkCurrent;
    const float smax = eta / phi * gdark_e *
                       (1.0f + powf(cdark / hillaff, hillcoef));
    float g  = gdark_e;
    float s  = gdark_e * eta / phi;
    float c  = cdark;
    float cs = cdark;
    float x0 = xrow[0];
    float r  = x0 * gam / sigma;
    float p  = (eta + r) / phi;
    orow[0] = 0.0f;
    for (int t = 1; t < TT; ++t) {
        float x  = xrow[(t - 1) * UU];
        float rn = r + DTSTEP * (-sigma * r) + gam * x;
        float pn = p + DTSTEP * (r + eta - phi * p);
        float cn = c + DTSTEP * (cur2ca * cgmp2cur * powf(g, cgmphill)
                                 / (1.0f + cs / cdark) - beta * c);
        float csn = cs - DTSTEP * (betaSlow * (cs - c));
        float sn  = smax / (1.0f + powf(cn / hillaff, hillcoef));
        float gn  = g + DTSTEP * (s - p * g);
        orow[t * UU] = -(cgmp2cur * powf(gn, cgmphill)) * 0.5f;
        g = gn; s = sn; c = cn; cs = csn; p = pn; r = rn;
    }
}

__global__ __launch_bounds__(256, 1) void prfr_kernel(
    const float* __restrict__ X,
    const float* __restrict__ sigma_p, const float* __restrict__ phi_p,
    const float* __restrict__ eta_p,   const float* __restrict__ beta_p,
    const float* __restrict__ cgmp2cur_p, const float* __restrict__ cgmphill_p,
    const float* __restrict__ cdark_p, const float* __restrict__ betaSlow_p,
    const float* __restrict__ hillcoef_p, const float* __restrict__ hillaff_p,
    const float* __restrict__ gamma_p, const float* __restrict__ gdark_p,
    float* __restrict__ out, int Bn)
{
    __shared__ __align__(16) float SX[16][256];   // X tile  [t_local][u_local]
    __shared__ __align__(16) float SO[16][256];   // out tile[t_local][u_local]
    __shared__ int anyslow;

    const int tid  = threadIdx.x;                     // 0..255 = u_local
    const int w    = __builtin_amdgcn_readfirstlane(tid >> 6);
    const int lane = tid & 63;
    const int b    = blockIdx.x >> 2;
    const int uq   = blockIdx.x & 3;
    const int u    = uq * 256 + tid;

    const float sigma = sigma_p[u], phi = phi_p[u], eta = eta_p[u];
    const float beta = beta_p[u], cgmp2cur = cgmp2cur_p[u];
    const float cgmphill = cgmphill_p[u], cdark = cdark_p[u];
    const float betaSlow = betaSlow_p[u], hillcoef = hillcoef_p[u];
    const float hillaff = hillaff_p[u], gam = gamma_p[u], gdark = gdark_p[u];

    const bool fastu = (cgmphill == 3.0f) && (hillcoef == 4.0f);
    if (tid == 0) anyslow = 0;
    __syncthreads();
    if (!fastu) anyslow = 1;
    __syncthreads();

    const size_t bTU = (size_t)b * (TT * UU);

    if (anyslow) {
        run_generic(X + bTU + u, out + bTU + u, sigma, phi, eta, beta,
                    cgmp2cur, cgmphill, cdark, betaSlow, hillcoef,
                    hillaff, gam, gdark);
        return;
    }

    // -------- FAST path: cgmphill=3, hillcoef=4 --------
    const float darkCurrent = gdark * gdark * gdark * cgmp2cur * 0.5f;
    const float gdark_e = gdark;                 // (2*dark/c2c)^(1/3) == gdark
    const float cur2ca = beta * cdark / darkCurrent;
    const float ha2 = (cdark / hillaff) * (cdark / hillaff);
    const float smax = eta / phi * gdark_e * (1.0f + ha2 * ha2);

    const float Ar   = 1.0f - DTSTEP * sigma;
    const float P1   = 1.0f - DTSTEP * phi;
    const float Ke   = DTSTEP * eta;
    const float icd  = 1.0f / cdark;
    const float KC   = DTSTEP * cur2ca * cgmp2cur;
    const float C1   = 1.0f - DTSTEP * beta;
    const float dtbs = DTSTEP * betaSlow;
    const float iha  = 1.0f / hillaff;
    const float outk = -0.5f * cgmp2cur;

    float g  = gdark_e;
    float s  = gdark_e * eta / phi;
    float c  = cdark;
    float cs = cdark;
    float x0 = X[bTU + u];
    float r  = x0 * gam / sigma;
    float p  = (eta + r) / phi;
    float gp = g * g * g;

    out[bTU + u] = 0.0f;   // out[b][0][u]

    // per-thread staging source: row (4w+j), 16B slot = lane
    const float* xs = X + bTU + uq * 256 + (size_t)(4 * w) * UU + lane * 4;
    // per-thread store base: row (w+1) + 16n + 4j, col16 = lane
    float* op = out + bTU + uq * 256 + (size_t)(w + 1) * UU + lane * 4;

    // Prologue: stage chunk 0
#pragma unroll
    for (int j = 0; j < 4; ++j) gload16(xs + j * UU, &SX[4 * w + j][0]);
    xs += 16 * UU;

    auto step = [&](float x, float& o) {
        float rn  = fmaf(Ar, r, gam * x);
        float pn  = fmaf(P1, p, fmaf(DTSTEP, r, Ke));
        float den = fmaf(cs, icd, 1.0f);
        float rd  = __builtin_amdgcn_rcpf(den);
        float cn  = fmaf(KC, gp * rd, C1 * c);
        float csn = fmaf(-dtbs, cs - c, cs);
        float t2  = cn * iha;
        t2 *= t2;
        float sn  = smax * __builtin_amdgcn_rcpf(fmaf(t2, t2, 1.0f));
        float gn  = fmaf(DTSTEP, fmaf(-p, g, s), g);   // OLD s, p
        float gpn = gn * gn * gn;
        o = outk * gpn;
        g = gn; s = sn; c = cn; cs = csn; p = pn; r = rn; gp = gpn;
    };

    for (int n = 0; n < 32; ++n) {
        // head: my stage(chunk n) retired. queue = [stage:4][stores(n-1):4]
        if (n == 0) asm volatile("s_waitcnt vmcnt(0)" ::: "memory");
        else        asm volatile("s_waitcnt vmcnt(4)" ::: "memory");
        __builtin_amdgcn_sched_barrier(0);
        __builtin_amdgcn_s_barrier();                 // A: SX chunk n visible

        float xa[16];
#pragma unroll
        for (int k = 0; k < 16; ++k) xa[k] = SX[k][tid];
        asm volatile("s_waitcnt lgkmcnt(0)" ::: "memory");
        __builtin_amdgcn_sched_barrier(0);
        __builtin_amdgcn_s_barrier();                 // B: all reads done

        if (n < 31) {                                 // stage chunk n+1
#pragma unroll
            for (int j = 0; j < 4; ++j) gload16(xs + j * UU, &SX[4 * w + j][0]);
            xs += 16 * UU;
        }

        // 16 steps (n=31: step 15 computes dead state from valid x[511])
#pragma unroll
        for (int k = 0; k < 16; ++k) {
            float o;
            step(xa[k], o);
            SO[k][tid] = o;
        }
        asm volatile("s_waitcnt lgkmcnt(0)" ::: "memory");
        __builtin_amdgcn_sched_barrier(0);
        __builtin_amdgcn_s_barrier();                 // C: SO tile complete

        const float4* SOv = (const float4*)&SO[0][0];
#pragma unroll
        for (int j = 0; j < 4; ++j) {                 // row t = 4j + w
            if (n == 31 && j == 3 && w == 3) continue;  // out row 512 DNE
            float4 v = SOv[j * 256 + tid];
            *(float4*)(op + j * 4 * UU) = v;
        }
        op += 16 * UU;
    }
}

extern "C" void kernel_launch(void* const* d_in, const int* in_sizes, int n_in,
                              void* d_out, int out_size, void* d_ws, size_t ws_size,
                              hipStream_t stream)
{
    const float* X = (const float*)d_in[0];
    const int B = in_sizes[0] / (TT * UU);
    const int grid = B * 4;            // (b, u-quarter) blocks, 256 thr each
    prfr_kernel<<<grid, 256, 0, stream>>>(
        X,
        (const float*)d_in[1],  (const float*)d_in[2],  (const float*)d_in[3],
        (const float*)d_in[4],  (const float*)d_in[5],  (const float*)d_in[6],
        (const float*)d_in[7],  (const float*)d_in[8],  (const float*)d_in[9],
        (const float*)d_in[10], (const float*)d_in[11], (const float*)d_in[12],
        (float*)d_out, B);
}